// Round 9
// baseline (271.779 us; speedup 1.0000x reference)
//
#include <hip/hip_runtime.h>
#include <hip/hip_bf16.h>

typedef __attribute__((ext_vector_type(8))) __bf16 bf16x8;
typedef __attribute__((ext_vector_type(4))) float f32x4;
typedef __attribute__((ext_vector_type(16))) float f32x16;
typedef __attribute__((ext_vector_type(4))) unsigned int u32x4;

#define DIM 1024
#define NHEADS 16
#define HDIM 64
#define BATCH 4
#define SEQ 2048
#define ROWS (BATCH * SEQ) /* 8192 */
#define SCL 0.18033688011112042f /* 0.125 * log2(e) */

__device__ inline unsigned short f2bf(float f) {
    __hip_bfloat16 h = __float2bfloat16(f);
    return *reinterpret_cast<unsigned short*>(&h);
}

// pack two floats to bf16x2 (RNE) -- v_cvt_pk_bf16_f32 on gfx950
__device__ inline unsigned int packbf2(float a, float b) {
    unsigned short ua = __builtin_bit_cast(unsigned short, (__bf16)a);
    unsigned short ub = __builtin_bit_cast(unsigned short, (__bf16)b);
    return (unsigned int)ua | ((unsigned int)ub << 16);
}

typedef const __attribute__((address_space(1))) unsigned int* gas_ptr;
typedef __attribute__((address_space(3))) unsigned int* las_ptr;
__device__ inline void gload16(const void* g, void* l) {
    __builtin_amdgcn_global_load_lds((gas_ptr)g, (las_ptr)l, 16, 0, 0);
}

// ---------------- fused prologue: cast x + transpose both weights (1 dispatch, was 3) -------
// region 0: blocks [0,8192)        cast x fp32 -> bf16 (4/thread)
// region 1: blocks [8192,11264)    W_qkv^T  (96 x 32 tile-blocks), Q cols pre-scaled by SCL
// region 2: blocks [11264,12288)   W_proj^T (32 x 32 tile-blocks)
__global__ __launch_bounds__(256) void prologue(const float* __restrict__ x,
                                                unsigned short* __restrict__ x_bf,
                                                const float* __restrict__ W_qkv,
                                                unsigned short* __restrict__ WqkvT,
                                                const float* __restrict__ W_proj,
                                                unsigned short* __restrict__ WprojT) {
    __shared__ float tile[32][33];
    const int blk = blockIdx.x;
    if (blk < 8192) {
        int i = blk * 256 + threadIdx.x;
        float4 v = ((const float4*)x)[i];
        ushort4 o;
        o.x = f2bf(v.x); o.y = f2bf(v.y); o.z = f2bf(v.z); o.w = f2bf(v.w);
        ((ushort4*)x_bf)[i] = o;
        return;
    }
    const float* in; unsigned short* outp; int C, srows, bx, byy; float scl;
    if (blk < 11264) {
        int t = blk - 8192;
        in = W_qkv; outp = WqkvT; C = 3 * DIM; srows = DIM; scl = SCL;
        bx = t % 96; byy = t / 96;
    } else {
        int t = blk - 11264;
        in = W_proj; outp = WprojT; C = DIM; srows = 0; scl = 1.f;
        bx = t & 31; byy = t >> 5;
    }
    const int R = DIM;
    int c0 = bx * 32, r0 = byy * 32;
    int tx = threadIdx.x & 31, ty = threadIdx.x >> 5; // 32 x 8
#pragma unroll
    for (int i = 0; i < 32; i += 8) {
        int r = r0 + ty + i, c = c0 + tx;
        tile[ty + i][tx] = in[(size_t)r * C + c];
    }
    __syncthreads();
#pragma unroll
    for (int i = 0; i < 32; i += 8) {
        int orow = c0 + ty + i, oc = r0 + tx;
        float v = tile[tx][ty + i];
        if (orow < srows) v *= scl;
        outp[(size_t)orow * R + oc] = f2bf(v);
    }
}

// ---------------- GEMM: C = A * Bt^T + bias, with fused K/V fragment-packing ----------------
// (R5-verified). BK=64 as two 32-chunks; epilogue packs K/V quadrants straight into
// Kp/Vp fragment layouts via wave-private LDS overlay. XCD-chunk swizzle.
__global__ __launch_bounds__(256) void gemm_bt_bias(const unsigned short* __restrict__ A,
                                                    const unsigned short* __restrict__ Bt,
                                                    const float* __restrict__ bias,
                                                    unsigned short* __restrict__ Cq,
                                                    unsigned short* __restrict__ Kp,
                                                    unsigned short* __restrict__ Vp,
                                                    float* __restrict__ Cf,
                                                    int M, int N, int K, int qcols) {
    __shared__ unsigned short SMEM[18432];
    unsigned short* As0 = SMEM;            // As[kc] = SMEM + kc*4096
    unsigned short* Bs0 = SMEM + 8192;     // Bs[kc] = SMEM + 8192 + kc*4096
    const int tid = threadIdx.x;
    const int lane = tid & 63, wave = tid >> 6;
    const int wm = (wave >> 1) * 64, wn = (wave & 1) * 64;
    const int nwg = gridDim.x * gridDim.y;
    const int gflat = blockIdx.y * gridDim.x + blockIdx.x;
    const int bidx = (gflat & 7) * (nwg >> 3) + (gflat >> 3); // contiguous chunk per XCD
    const int bx = bidx % gridDim.x, byy = bidx / gridDim.x;
    const int rowA = byy * 128, rowB = bx * 128;
    const int fr = lane & 15, fo = (lane >> 4) * 8;

    f32x4 acc[4][4] = {};

    for (int k0 = 0; k0 < K; k0 += 64) {
#pragma unroll
        for (int kc = 0; kc < 2; kc++) {
#pragma unroll
            for (int c = 0; c < 2; c++) {
                int o = c * 4096 + tid * 16; // byte offset in 8KB chunk
                int r = o >> 6, cb = o & 63; // 64 B per row (32 bf16)
                int ldsb = c * 4096 + wave * 1024;
                gload16((const char*)A + ((size_t)(rowA + r) * K + k0 + kc * 32) * 2 + cb,
                        (char*)As0 + kc * 8192 + ldsb);
                gload16((const char*)Bt + ((size_t)(rowB + r) * K + k0 + kc * 32) * 2 + cb,
                        (char*)Bs0 + kc * 8192 + ldsb);
            }
        }
        __syncthreads();
#pragma unroll
        for (int kc = 0; kc < 2; kc++) {
            bf16x8 af[4], bfr[4];
#pragma unroll
            for (int i = 0; i < 4; i++) {
                af[i]  = *(const bf16x8*)(As0 + kc * 4096 + (wm + i * 16 + fr) * 32 + fo);
                bfr[i] = *(const bf16x8*)(Bs0 + kc * 4096 + (wn + i * 16 + fr) * 32 + fo);
            }
#pragma unroll
            for (int mi = 0; mi < 4; mi++)
#pragma unroll
                for (int ni = 0; ni < 4; ni++)
                    acc[mi][ni] = __builtin_amdgcn_mfma_f32_16x16x32_bf16(af[mi], bfr[ni],
                                                                          acc[mi][ni], 0, 0, 0);
        }
        __syncthreads();
    }

    // C/D layout (16x16): col = lane&15, row = (lane>>4)*4 + reg
    const int cn = lane & 15, cm = (lane >> 4) * 4;
    const int gn0 = rowB + wn; // wave's 64-col region: uniform Q/K/V classification

    if (Cf) {
        for (int ni = 0; ni < 4; ni++) {
            int gn = gn0 + ni * 16 + cn;
            float bv = bias[gn];
            if (gn < qcols) bv *= SCL;
            for (int mi = 0; mi < 4; mi++) {
#pragma unroll
                for (int r = 0; r < 4; r++) {
                    int gm = rowA + wm + mi * 16 + cm + r;
                    Cf[(size_t)gm * N + gn] = acc[mi][ni][r] + bv;
                }
            }
        }
    } else if (gn0 < 1024) {
        for (int ni = 0; ni < 4; ni++) {
            int gn = gn0 + ni * 16 + cn;
            float bv = bias[gn];
            if (gn < qcols) bv *= SCL;
            for (int mi = 0; mi < 4; mi++) {
#pragma unroll
                for (int r = 0; r < 4; r++) {
                    int gm = rowA + wm + mi * 16 + cm + r;
                    Cq[(size_t)gm * 1024 + gn] = f2bf(acc[mi][ni][r] + bv);
                }
            }
        }
    } else {
        // K or V: stage quadrant (bias added, bf16) into wave-private LDS tile [64][72]
        unsigned short* Lw = SMEM + wave * (64 * 72);
        for (int ni = 0; ni < 4; ni++) {
            float bv = bias[gn0 + ni * 16 + cn];
            for (int mi = 0; mi < 4; mi++) {
#pragma unroll
                for (int r = 0; r < 4; r++)
                    Lw[(mi * 16 + cm + r) * 72 + ni * 16 + cn] = f2bf(acc[mi][ni][r] + bv);
            }
        }
        __builtin_amdgcn_s_waitcnt(0); // drain lgkm: own ds_writes visible to own ds_reads
        const int b = rowA >> 11, s0g = rowA & 2047;
        const int mm = lane & 31, hh = lane >> 5;
        if (gn0 < 2048) {
            const int h = (gn0 - 1024) >> 6;
            const size_t by = (size_t)(b * 16 + h);
            const int kub = (s0g + wm) >> 5;
#pragma unroll
            for (int f = 0; f < 8; f++) {
                int ktl = f >> 2, ks = f & 3;
                uint4 d = *(const uint4*)&Lw[(ktl * 32 + mm) * 72 + ks * 16 + hh * 8];
                *(uint4*)(Kp + ((by * 64 + kub + ktl) * 4 + ks) * 512 + lane * 8) = d;
            }
        } else {
            const int h = (gn0 - 2048) >> 6;
            const size_t by = (size_t)(b * 16 + h);
            const int vub = (s0g + wm) >> 4;
#pragma unroll
            for (int f = 0; f < 8; f++) {
                int ksl = f >> 1, dt = f & 1;
                unsigned short tmp[8];
#pragma unroll
                for (int j = 0; j < 8; j++)
                    tmp[j] = Lw[(ksl * 16 + (j & 3) + 8 * (j >> 2) + 4 * hh) * 72 + dt * 32 + mm];
                *(uint4*)(Vp + ((by * 128 + vub + ksl) * 2 + dt) * 512 + lane * 8) =
                    *(uint4*)tmp;
            }
        }
    }
}

// ---- softmax + PV for one q-tile: exp2 of S^T C-frag, pack to bf16 (= PV A-frag).
// Denominator via MFMA-ones (l = P @ 1): the two l-MFMAs accumulate into lacc whose
// C-layout (row=q, col replicated) matches oacc register-for-register -- removes the
// 16-add VALU reduction per step AND the 17-shuffle epilogue. Num & denom now use the
// SAME bf16-rounded P (errors correlate -> no accuracy loss).
__device__ inline void softmax_pv(const f32x16& cfrag, const bf16x8 vf[2][2], const bf16x8 ones,
                                  f32x16& o0, f32x16& o1, f32x16& lacc) {
    unsigned int pk[8];
#pragma unroll
    for (int p = 0; p < 8; p++) {
        float e0 = __builtin_amdgcn_exp2f(cfrag[2 * p]);
        float e1 = __builtin_amdgcn_exp2f(cfrag[2 * p + 1]);
        pk[p] = packbf2(e0, e1);
    }
    u32x4 lo = {pk[0], pk[1], pk[2], pk[3]};
    u32x4 hi = {pk[4], pk[5], pk[6], pk[7]};
    bf16x8 pa0 = __builtin_bit_cast(bf16x8, lo); // keys [ku*32, +16) permuted
    bf16x8 pa1 = __builtin_bit_cast(bf16x8, hi); // keys [ku*32+16, +16)
    o0   = __builtin_amdgcn_mfma_f32_32x32x16_bf16(pa0, vf[0][0], o0, 0, 0, 0);
    o1   = __builtin_amdgcn_mfma_f32_32x32x16_bf16(pa0, vf[0][1], o1, 0, 0, 0);
    lacc = __builtin_amdgcn_mfma_f32_32x32x16_bf16(pa0, ones,     lacc, 0, 0, 0);
    o0   = __builtin_amdgcn_mfma_f32_32x32x16_bf16(pa1, vf[1][0], o0, 0, 0, 0);
    o1   = __builtin_amdgcn_mfma_f32_32x32x16_bf16(pa1, vf[1][1], o1, 0, 0, 0);
    lacc = __builtin_amdgcn_mfma_f32_32x32x16_bf16(pa1, ones,     lacc, 0, 0, 0);
}

// ---- one 32-key step, qt-interleaved: QK0,QK1 issue back-to-back (two independent
// 4-MFMA chains hide each other); then sm0, PV0 (MFMAs in flight), sm1 (VALU overlaps
// PV0), PV1. MFMA issue is non-blocking within a wave -> compile-time MFMA||VALU overlap.
__device__ inline void attn_step(const bf16x8 kf[4], const bf16x8 vf[2][2], const bf16x8 ones,
                                 const bf16x8 qf[2][4], f32x16 oacc[2][2], f32x16 lacc[2]) {
    f32x16 cf0 = {}, cf1 = {};
#pragma unroll
    for (int ks = 0; ks < 4; ks++)
        cf0 = __builtin_amdgcn_mfma_f32_32x32x16_bf16(kf[ks], qf[0][ks], cf0, 0, 0, 0);
#pragma unroll
    for (int ks = 0; ks < 4; ks++)
        cf1 = __builtin_amdgcn_mfma_f32_32x32x16_bf16(kf[ks], qf[1][ks], cf1, 0, 0, 0);
    softmax_pv(cf0, vf, ones, oacc[0][0], oacc[0][1], lacc[0]);
    softmax_pv(cf1, vf, ones, oacc[1][0], oacc[1][1], lacc[1]);
}

// ---------------- flash attention v14: v11 + MFMA-ones denominator -------------------------
// OPERATING-POINT NOTE (triple-confirmed): 64q x 64d per wave at 2 waves/SIMD, ~190-220 regs.
//   R2: cap 128 -> acc spill, 1.5 GB scratch, 619 µs.  R4: cap 170 -> 60 MB scratch, 123 µs.
//   R7: 32q tile (more waves, less regs) -> arithmetic intensity halved, 150 µs.
// Do NOT shrink the tile; do NOT add a min-waves launch_bounds hint.
// v14: denominator moved from the VALU (51% busy, dominant pipe) to the MFMA pipe (36%):
// 2 extra mfma(pa, ones) per qt-step; lacc layout-matches oacc so epilogue is a per-reg rcp.
__global__ __launch_bounds__(256, 2) void attn_kernel(const unsigned short* __restrict__ Qb, // [8192][1024] prescaled
                                                      const unsigned short* __restrict__ Kp,
                                                      const unsigned short* __restrict__ Vp,
                                                      unsigned short* __restrict__ attnb) { // [8192][1024]
    __shared__ float Po[2][12 * 256]; // [qpair] partial O (8 slots) + l (4 slots) per qt round
    const int tid = threadIdx.x;
    const int lane = tid & 63, wave = tid >> 6;
    const int qpair = wave >> 1, ksplit = wave & 1;
    const int m31 = lane & 31, h = lane >> 5;
    // dispatch order: x fastest. gflat == dispatch index; round-robin over XCDs.
    const int gflat = blockIdx.y * gridDim.x + blockIdx.x; // [0, 1024)
    const int xcd = gflat & 7, slot = gflat >> 3;          // slot in [0, 128)
    const int by = xcd * 8 + (slot >> 4);                  // [0, 64): 8 panels/XCD
    const int qb = slot & 15;                              // [0, 16)
    const int b = by >> 4;
    const int bS = b * SEQ, hcol = (by & 15) * HDIM;
    const int q0 = qb * 128 + qpair * 64;

    // Q B-frags: qf[qt][ks]: B[k=ks*16+h*8+j][n=q0+qt*32+m31]
    bf16x8 qf[2][4];
#pragma unroll
    for (int qt = 0; qt < 2; qt++)
#pragma unroll
        for (int ks = 0; ks < 4; ks++)
            qf[qt][ks] = *(const bf16x8*)(Qb + (size_t)(bS + q0 + qt * 32 + m31) * 1024 +
                                          hcol + ks * 16 + h * 8);

    bf16x8 ones;
#pragma unroll
    for (int j = 0; j < 8; j++) ones[j] = (__bf16)1.0f;

    f32x16 oacc[2][2] = {}; // [qt][dt]: C row=q, col=d=dt*32+m31
    f32x16 lacc[2] = {};    // [qt]: l[q] replicated across cols, same row layout as oacc

    const unsigned short* kbase = Kp + (size_t)by * 64 * 2048 + lane * 8;
    const unsigned short* vbase = Vp + (size_t)by * 128 * 1024 + lane * 8;

    const int ku0 = ksplit * 32; // each wave: 32 key-units of 32 keys
    bf16x8 kfa[4], kfb[4];
    {
        const unsigned short* kp = kbase + (size_t)ku0 * 2048;
#pragma unroll
        for (int ks = 0; ks < 4; ks++) kfa[ks] = *(const bf16x8*)(kp + ks * 512);
    }
    for (int ki = 0; ki < 32; ki += 2) {
        // even step: compute with kfa, prefetch K(ki+1) -> kfb
        {
            int ku = ku0 + ki;
            bf16x8 vf[2][2];
#pragma unroll
            for (int ks = 0; ks < 2; ks++) {
                const unsigned short* vp = vbase + ((size_t)ku * 2 + ks) * 1024;
                vf[ks][0] = *(const bf16x8*)(vp);
                vf[ks][1] = *(const bf16x8*)(vp + 512);
            }
            const unsigned short* kpn = kbase + (size_t)(ku + 1) * 2048;
#pragma unroll
            for (int ks = 0; ks < 4; ks++) kfb[ks] = *(const bf16x8*)(kpn + ks * 512);
            attn_step(kfa, vf, ones, qf, oacc, lacc);
        }
        // odd step: compute with kfb, prefetch K(ki+2) -> kfa (clamped, branchless)
        {
            int ku = ku0 + ki + 1;
            bf16x8 vf[2][2];
#pragma unroll
            for (int ks = 0; ks < 2; ks++) {
                const unsigned short* vp = vbase + ((size_t)ku * 2 + ks) * 1024;
                vf[ks][0] = *(const bf16x8*)(vp);
                vf[ks][1] = *(const bf16x8*)(vp + 512);
            }
            int kup = ku0 + ((ki + 2 < 32) ? (ki + 2) : 31); // last iter: redundant reload
            const unsigned short* kpn = kbase + (size_t)kup * 2048;
#pragma unroll
            for (int ks = 0; ks < 4; ks++) kfa[ks] = *(const bf16x8*)(kpn + ks * 512);
            attn_step(kfb, vf, ones, qf, oacc, lacc);
        }
    }

    // two-round combine (qt=0 then qt=1): ksplit=1 parks partials (O + l), ksplit=0 sums.
#pragma unroll
    for (int qt = 0; qt < 2; qt++) {
        if (ksplit == 1) {
#pragma unroll
            for (int dt = 0; dt < 2; dt++)
#pragma unroll
                for (int c = 0; c < 4; c++) {
                    f32x4 v = {oacc[qt][dt][c * 4 + 0], oacc[qt][dt][c * 4 + 1],
                               oacc[qt][dt][c * 4 + 2], oacc[qt][dt][c * 4 + 3]};
                    *(f32x4*)&Po[qpair][(dt * 4 + c) * 256 + lane * 4] = v;
                }
#pragma unroll
            for (int c = 0; c < 4; c++) {
                f32x4 v = {lacc[qt][c * 4 + 0], lacc[qt][c * 4 + 1],
                           lacc[qt][c * 4 + 2], lacc[qt][c * 4 + 3]};
                *(f32x4*)&Po[qpair][(8 + c) * 256 + lane * 4] = v;
            }
        }
        __syncthreads();
        if (ksplit == 0) {
#pragma unroll
            for (int dt = 0; dt < 2; dt++)
#pragma unroll
                for (int c = 0; c < 4; c++) {
                    f32x4 v = *(const f32x4*)&Po[qpair][(dt * 4 + c) * 256 + lane * 4];
#pragma unroll
                    for (int j = 0; j < 4; j++) oacc[qt][dt][c * 4 + j] += v[j];
                }
#pragma unroll
            for (int c = 0; c < 4; c++) {
                f32x4 v = *(const f32x4*)&Po[qpair][(8 + c) * 256 + lane * 4];
#pragma unroll
                for (int j = 0; j < 4; j++) lacc[qt][c * 4 + j] += v[j];
            }
        }
        if (qt == 0) __syncthreads(); // Po reused by round 2
    }

    if (ksplit == 0) {
        // epilogue: rl per reg (lacc layout == oacc layout); C rows: row=(r&3)+8*(r>>2)+4h
#pragma unroll
        for (int qt = 0; qt < 2; qt++) {
#pragma unroll
            for (int r = 0; r < 16; r++) {
                float rlr = __builtin_amdgcn_rcpf(lacc[qt][r]);
                int row = (r & 3) + 8 * (r >> 2) + 4 * h;
                size_t orow = (size_t)(bS + q0 + qt * 32 + row) * 1024 + hcol;
                attnb[orow + m31]      = f2bf(oacc[qt][0][r] * rlr);
                attnb[orow + 32 + m31] = f2bf(oacc[qt][1][r] * rlr);
            }
        }
    }
}

extern "C" void kernel_launch(void* const* d_in, const int* in_sizes, int n_in,
                              void* d_out, int out_size, void* d_ws, size_t ws_size,
                              hipStream_t stream) {
    const float* x      = (const float*)d_in[0]; // [4,2048,1024]
    const float* W_qkv  = (const float*)d_in[1]; // [1024,3072]
    const float* b_qkv  = (const float*)d_in[2]; // [3072]
    const float* W_proj = (const float*)d_in[3]; // [1024,1024]
    const float* b_proj = (const float*)d_in[4]; // [1024]
    float* out = (float*)d_out;                  // [4,2048,1024]

    char* ws = (char*)d_ws;
    // lifetimes: x_bf,WqkvT die after gemm1 (Kp/Vp written DURING gemm1 -> own regions);
    // attnb aliases x_bf. Peak 75.5 MiB.
    unsigned short* x_bf   = (unsigned short*)(ws);                // [0, 16.8M)
    unsigned short* WqkvT  = (unsigned short*)(ws + 16777216);     // [16.8M, 23.1M)
    unsigned short* Qb     = (unsigned short*)(ws + 23068672);     // [23.1M, 39.8M)
    unsigned short* Kp     = (unsigned short*)(ws + 39845888);     // [39.8M, 56.6M)
    unsigned short* Vp     = (unsigned short*)(ws + 56623104);     // [56.6M, 73.4M)
    unsigned short* WprojT = (unsigned short*)(ws + 73400320);     // [73.4M, 75.5M)
    unsigned short* attnb  = (unsigned short*)(ws);                // reuses x_bf

    // 1) fused prologue: cast x + transpose W_qkv (Q cols pre-scaled) + transpose W_proj
    prologue<<<12288, 256, 0, stream>>>(x, x_bf, W_qkv, WqkvT, W_proj, WprojT);

    // 2) qkv = x @ W_qkv + b_qkv -> Qb (bf16, scaled) + Kp/Vp (fragment-packed, fused)
    gemm_bt_bias<<<dim3(3 * DIM / 128, ROWS / 128), 256, 0, stream>>>(
        x_bf, WqkvT, b_qkv, Qb, Kp, Vp, nullptr, ROWS, 3 * DIM, DIM, DIM);

    // 3) attention (x_bf dead; attnb reuses it): 128 q/block, KV split across wave pairs
    attn_kernel<<<dim3(SEQ / 128, BATCH * NHEADS), 256, 0, stream>>>(Qb, Kp, Vp, attnb);

    // 4) out = attn @ W_proj + b_proj (fp32 out)
    gemm_bt_bias<<<dim3(DIM / 128, ROWS / 128), 256, 0, stream>>>(
        attnb, WprojT, b_proj, nullptr, nullptr, nullptr, out, ROWS, DIM, DIM, 0);
}

// Round 10
// 261.462 us; speedup vs baseline: 1.0395x; 1.0395x over previous
//
#include <hip/hip_runtime.h>
#include <hip/hip_bf16.h>

typedef __attribute__((ext_vector_type(8))) __bf16 bf16x8;
typedef __attribute__((ext_vector_type(4))) float f32x4;
typedef __attribute__((ext_vector_type(16))) float f32x16;
typedef __attribute__((ext_vector_type(4))) unsigned int u32x4;

#define DIM 1024
#define NHEADS 16
#define HDIM 64
#define BATCH 4
#define SEQ 2048
#define ROWS (BATCH * SEQ) /* 8192 */
#define SCL 0.18033688011112042f /* 0.125 * log2(e) */

__device__ inline unsigned short f2bf(float f) {
    __hip_bfloat16 h = __float2bfloat16(f);
    return *reinterpret_cast<unsigned short*>(&h);
}

// pack two floats to bf16x2 (RNE) -- v_cvt_pk_bf16_f32 on gfx950
__device__ inline unsigned int packbf2(float a, float b) {
    unsigned short ua = __builtin_bit_cast(unsigned short, (__bf16)a);
    unsigned short ub = __builtin_bit_cast(unsigned short, (__bf16)b);
    return (unsigned int)ua | ((unsigned int)ub << 16);
}

typedef const __attribute__((address_space(1))) unsigned int* gas_ptr;
typedef __attribute__((address_space(3))) unsigned int* las_ptr;
__device__ inline void gload16(const void* g, void* l) {
    __builtin_amdgcn_global_load_lds((gas_ptr)g, (las_ptr)l, 16, 0, 0);
}

// ---------------- fused prologue: cast x + transpose both weights (1 dispatch) -------------
__global__ __launch_bounds__(256) void prologue(const float* __restrict__ x,
                                                unsigned short* __restrict__ x_bf,
                                                const float* __restrict__ W_qkv,
                                                unsigned short* __restrict__ WqkvT,
                                                const float* __restrict__ W_proj,
                                                unsigned short* __restrict__ WprojT) {
    __shared__ float tile[32][33];
    const int blk = blockIdx.x;
    if (blk < 8192) {
        int i = blk * 256 + threadIdx.x;
        float4 v = ((const float4*)x)[i];
        ushort4 o;
        o.x = f2bf(v.x); o.y = f2bf(v.y); o.z = f2bf(v.z); o.w = f2bf(v.w);
        ((ushort4*)x_bf)[i] = o;
        return;
    }
    const float* in; unsigned short* outp; int C, srows, bx, byy; float scl;
    if (blk < 11264) {
        int t = blk - 8192;
        in = W_qkv; outp = WqkvT; C = 3 * DIM; srows = DIM; scl = SCL;
        bx = t % 96; byy = t / 96;
    } else {
        int t = blk - 11264;
        in = W_proj; outp = WprojT; C = DIM; srows = 0; scl = 1.f;
        bx = t & 31; byy = t >> 5;
    }
    const int R = DIM;
    int c0 = bx * 32, r0 = byy * 32;
    int tx = threadIdx.x & 31, ty = threadIdx.x >> 5; // 32 x 8
#pragma unroll
    for (int i = 0; i < 32; i += 8) {
        int r = r0 + ty + i, c = c0 + tx;
        tile[ty + i][tx] = in[(size_t)r * C + c];
    }
    __syncthreads();
#pragma unroll
    for (int i = 0; i < 32; i += 8) {
        int orow = c0 + ty + i, oc = r0 + tx;
        float v = tile[tx][ty + i];
        if (orow < srows) v *= scl;
        outp[(size_t)orow * R + oc] = f2bf(v);
    }
}

// =================== gemm1: 256x256-tile 8-phase pipelined QKV GEMM + K/V pack ==============
// T3+T4 schedule derived from the m201 template: BK=64, 8 waves (2Mx4N), per-wave 128x64.
// LDS 128 KiB = 2 tile-buffers x (A 32K + B 32K); each operand tile = 2 INTERLEAVED halves:
//   A-halfL = rows {0-63,128-191} (the rows read only in miL phases), halfH = the rest.
//   B-halfL = cols with bit5==0 (read only in niL phases).
// Per K-tile u: 4 phases {ds_read; issue 1 half-tile stage; barrier; setprio; 16 MFMA;
// setprio; barrier}. Stage targets = regions whose last reader finished a phase earlier:
//   P1: AH(u+1)  P2: BH(u+1)  P3: AL(u+2)  P4: BL(u+2), vmcnt(4) before P4's last barrier
// (allows only the 2 newest half-tiles in flight -> tile u+1 fully landed before its reads;
// NEVER drains to 0 in the main loop). Bank conflicts: granule ^= (slot&7) XOR-swizzle,
// applied as inverse-swizzled GLOBAL SOURCE + swizzled ds_read (gload_lds dest stays linear).
// B-fragments are register-reused across phases (24 ds_read_b128 per tile, not 48).
__global__ __launch_bounds__(512, 2) void qkv_gemm_pack(const unsigned short* __restrict__ A,   // x_bf [8192][1024]
                                                        const unsigned short* __restrict__ Bt,  // WqkvT [3072][1024]
                                                        const float* __restrict__ bias,
                                                        unsigned short* __restrict__ Cq,
                                                        unsigned short* __restrict__ Kp,
                                                        unsigned short* __restrict__ Vp) {
    __shared__ __align__(16) char SMEM[131072];
    const int tid = threadIdx.x;
    const int lane = tid & 63, wave = tid >> 6;
    const int wr = wave >> 2, wc = wave & 3;
    const int fr = lane & 15, lh = lane >> 4;
    // XCD-chunk swizzle, nwg = 384 (%8==0)
    const int gflat = blockIdx.y * gridDim.x + blockIdx.x;
    const int bidx = (gflat & 7) * 48 + (gflat >> 3);
    const int bx = bidx % 12, byy = bidx / 12;
    const int rowA = byy * 256, colB = bx * 256;

    // staging precompute: slot s = wave*8 + lane/8 (+64 for 2nd load); granule = lane&7;
    // source granule = granule ^ (s&7) = (lane&7)^(lane>>3)
    const int sA = wave * 8 + (lane >> 3);
    const int arow0 = sA;                              // A logical row base (j adds 128)
    const int crow0 = (sA & 31) + (sA >> 5) * 64;      // B logical col base
    const int glb = ((lane & 7) ^ (lane >> 3)) * 16;   // src granule byte offset
    // ds_read precompute: reader slot&7 = fr&7; k-granule ks*4+lh, swizzled
    const int ga0 = ((lh) ^ (fr & 7)) * 16;
    const int ga1 = ((4 + lh) ^ (fr & 7)) * 16;
    const int aoff = (wr * 64 + fr) * 128;
    const int boff = (wc * 32 + fr) * 128;

    f32x4 acc[8][4] = {};

    auto stA = [&](int tb, int h, int tt) {
        char* d = SMEM + tb * 65536 + h * 16384 + wave * 1024;
        const char* g0 = (const char*)A +
            (((size_t)(rowA + arow0 + h * 64)) * 1024 + (size_t)tt * 64) * 2 + glb;
        gload16(g0, d);
        gload16(g0 + (size_t)128 * 2048, d + 8192);
    };
    auto stB = [&](int tb, int h, int tt) {
        char* d = SMEM + tb * 65536 + 32768 + h * 16384 + wave * 1024;
        const char* g0 = (const char*)Bt +
            (((size_t)(colB + crow0 + h * 32)) * 1024 + (size_t)tt * 64) * 2 + glb;
        gload16(g0, d);
        gload16(g0 + (size_t)128 * 2048, d + 8192);
    };

    // prologue: tile0 (all 4 halves) + tile1 (AL, BL); allow the newest 2 halves in flight
    stA(0, 0, 0); stB(0, 0, 0); stA(0, 1, 0); stB(0, 1, 0);
    stA(1, 0, 1); stB(1, 0, 1);
    asm volatile("s_waitcnt vmcnt(4)" ::: "memory");
    __builtin_amdgcn_s_barrier();

    bf16x8 afq[4][2], bfa[2][2], bfb[2][2];
    for (int u = 0; u < 16; ++u) {
        const int cur = u & 1;
        const char* Al = SMEM + cur * 65536;
        const char* Bl = SMEM + cur * 65536 + 32768;
        // ---- phase 1: read A-halfL + B-halfL; MFMA (miL, niL); stage AH(u+1)
#pragma unroll
        for (int i = 0; i < 4; i++) {
            afq[i][0] = *(const bf16x8*)(Al + aoff + i * 2048 + ga0);
            afq[i][1] = *(const bf16x8*)(Al + aoff + i * 2048 + ga1);
        }
#pragma unroll
        for (int j = 0; j < 2; j++) {
            bfa[j][0] = *(const bf16x8*)(Bl + boff + j * 2048 + ga0);
            bfa[j][1] = *(const bf16x8*)(Bl + boff + j * 2048 + ga1);
        }
        if (u + 1 < 16) stA(cur ^ 1, 1, u + 1);
        __builtin_amdgcn_s_barrier();
        __builtin_amdgcn_s_setprio(1);
#pragma unroll
        for (int i = 0; i < 4; i++)
#pragma unroll
            for (int j = 0; j < 2; j++) {
                acc[i][j] = __builtin_amdgcn_mfma_f32_16x16x32_bf16(afq[i][0], bfa[j][0], acc[i][j], 0, 0, 0);
                acc[i][j] = __builtin_amdgcn_mfma_f32_16x16x32_bf16(afq[i][1], bfa[j][1], acc[i][j], 0, 0, 0);
            }
        __builtin_amdgcn_s_setprio(0);
        __builtin_amdgcn_s_barrier();
        // ---- phase 2: read B-halfH; MFMA (miL, niH); stage BH(u+1)
#pragma unroll
        for (int j = 0; j < 2; j++) {
            bfb[j][0] = *(const bf16x8*)(Bl + 16384 + boff + j * 2048 + ga0);
            bfb[j][1] = *(const bf16x8*)(Bl + 16384 + boff + j * 2048 + ga1);
        }
        if (u + 1 < 16) stB(cur ^ 1, 1, u + 1);
        __builtin_amdgcn_s_barrier();
        __builtin_amdgcn_s_setprio(1);
#pragma unroll
        for (int i = 0; i < 4; i++)
#pragma unroll
            for (int j = 0; j < 2; j++) {
                acc[i][2 + j] = __builtin_amdgcn_mfma_f32_16x16x32_bf16(afq[i][0], bfb[j][0], acc[i][2 + j], 0, 0, 0);
                acc[i][2 + j] = __builtin_amdgcn_mfma_f32_16x16x32_bf16(afq[i][1], bfb[j][1], acc[i][2 + j], 0, 0, 0);
            }
        __builtin_amdgcn_s_setprio(0);
        __builtin_amdgcn_s_barrier();
        // ---- phase 3: read A-halfH (overwrite afq); MFMA (miH, niL); stage AL(u+2)
#pragma unroll
        for (int i = 0; i < 4; i++) {
            afq[i][0] = *(const bf16x8*)(Al + 16384 + aoff + i * 2048 + ga0);
            afq[i][1] = *(const bf16x8*)(Al + 16384 + aoff + i * 2048 + ga1);
        }
        if (u + 2 < 16) stA(cur, 0, u + 2);
        __builtin_amdgcn_s_barrier();
        __builtin_amdgcn_s_setprio(1);
#pragma unroll
        for (int i = 0; i < 4; i++)
#pragma unroll
            for (int j = 0; j < 2; j++) {
                acc[4 + i][j] = __builtin_amdgcn_mfma_f32_16x16x32_bf16(afq[i][0], bfa[j][0], acc[4 + i][j], 0, 0, 0);
                acc[4 + i][j] = __builtin_amdgcn_mfma_f32_16x16x32_bf16(afq[i][1], bfa[j][1], acc[4 + i][j], 0, 0, 0);
            }
        __builtin_amdgcn_s_setprio(0);
        __builtin_amdgcn_s_barrier();
        // ---- phase 4: no reads; MFMA (miH, niH); stage BL(u+2); boundary vmcnt
        if (u + 2 < 16) stB(cur, 0, u + 2);
        __builtin_amdgcn_s_barrier();
        __builtin_amdgcn_s_setprio(1);
#pragma unroll
        for (int i = 0; i < 4; i++)
#pragma unroll
            for (int j = 0; j < 2; j++) {
                acc[4 + i][2 + j] = __builtin_amdgcn_mfma_f32_16x16x32_bf16(afq[i][0], bfb[j][0], acc[4 + i][2 + j], 0, 0, 0);
                acc[4 + i][2 + j] = __builtin_amdgcn_mfma_f32_16x16x32_bf16(afq[i][1], bfb[j][1], acc[4 + i][2 + j], 0, 0, 0);
            }
        __builtin_amdgcn_s_setprio(0);
        if (u < 14) asm volatile("s_waitcnt vmcnt(4)" ::: "memory");
        else        asm volatile("s_waitcnt vmcnt(0)" ::: "memory");
        __builtin_amdgcn_s_barrier();
    }

    // ---------------- epilogue: Q store / K,V pack (wave-private LDS overlay) ----------------
    const int cm = (lane >> 4) * 4, cn = lane & 15;
    const int gn0 = colB + wc * 64; // wave's 64-col region, uniform Q/K/V class
    if (gn0 < 1024) {
        // Q: bf16, bias scaled into exp2 domain (whole class is Q -> always SCL)
        for (int ni = 0; ni < 4; ni++) {
            int gn = gn0 + ni * 16 + cn;
            float bv = bias[gn] * SCL;
            for (int mi = 0; mi < 8; mi++) {
#pragma unroll
                for (int r = 0; r < 4; r++) {
                    int gm = rowA + wr * 128 + mi * 16 + cm + r;
                    Cq[(size_t)gm * 1024 + gn] = f2bf(acc[mi][ni][r] + bv);
                }
            }
        }
    } else {
        const int mm = lane & 31, hh = lane >> 5;
        unsigned short* Lw = (unsigned short*)SMEM + wave * (64 * 72);
        for (int kg = 0; kg < 2; kg++) {
            for (int ni = 0; ni < 4; ni++) {
                float bv = bias[gn0 + ni * 16 + cn];
                for (int mi = 0; mi < 4; mi++) {
#pragma unroll
                    for (int r = 0; r < 4; r++)
                        Lw[(mi * 16 + cm + r) * 72 + ni * 16 + cn] =
                            f2bf(acc[kg * 4 + mi][ni][r] + bv);
                }
            }
            __builtin_amdgcn_s_waitcnt(0); // own ds_writes visible to own ds_reads
            const int keybase = rowA + wr * 128 + kg * 64;
            const int b = keybase >> 11, s0g = keybase & 2047;
            if (gn0 < 2048) {
                const int h = (gn0 - 1024) >> 6;
                const size_t by = (size_t)(b * 16 + h);
                const int kub = s0g >> 5;
#pragma unroll
                for (int f = 0; f < 8; f++) {
                    int ktl = f >> 2, ks = f & 3;
                    uint4 d = *(const uint4*)&Lw[(ktl * 32 + mm) * 72 + ks * 16 + hh * 8];
                    *(uint4*)(Kp + ((by * 64 + kub + ktl) * 4 + ks) * 512 + lane * 8) = d;
                }
            } else {
                const int h = (gn0 - 2048) >> 6;
                const size_t by = (size_t)(b * 16 + h);
                const int vub = s0g >> 4;
#pragma unroll
                for (int f = 0; f < 8; f++) {
                    int ksl = f >> 1, dt = f & 1;
                    unsigned short tmp[8];
#pragma unroll
                    for (int j = 0; j < 8; j++)
                        tmp[j] = Lw[(ksl * 16 + (j & 3) + 8 * (j >> 2) + 4 * hh) * 72 + dt * 32 + mm];
                    *(uint4*)(Vp + ((by * 128 + vub + ksl) * 2 + dt) * 512 + lane * 8) =
                        *(uint4*)tmp;
                }
            }
            __builtin_amdgcn_s_waitcnt(0); // drain reads before kg1 overwrites Lw
        }
    }
}

// ---------------- GEMM (128^2, R5-verified): used for gemm2 (fp32 out + bias) ----------------
__global__ __launch_bounds__(256) void gemm_bt_bias(const unsigned short* __restrict__ A,
                                                    const unsigned short* __restrict__ Bt,
                                                    const float* __restrict__ bias,
                                                    float* __restrict__ Cf,
                                                    int M, int N, int K) {
    __shared__ unsigned short SMEM[16384];
    unsigned short* As0 = SMEM;            // As[kc] = SMEM + kc*4096
    unsigned short* Bs0 = SMEM + 8192;     // Bs[kc] = SMEM + 8192 + kc*4096
    const int tid = threadIdx.x;
    const int lane = tid & 63, wave = tid >> 6;
    const int wm = (wave >> 1) * 64, wn = (wave & 1) * 64;
    const int nwg = gridDim.x * gridDim.y;
    const int gflat = blockIdx.y * gridDim.x + blockIdx.x;
    const int bidx = (gflat & 7) * (nwg >> 3) + (gflat >> 3); // contiguous chunk per XCD
    const int bx = bidx % gridDim.x, byy = bidx / gridDim.x;
    const int rowA = byy * 128, rowB = bx * 128;
    const int fr = lane & 15, fo = (lane >> 4) * 8;

    f32x4 acc[4][4] = {};

    for (int k0 = 0; k0 < K; k0 += 64) {
#pragma unroll
        for (int kc = 0; kc < 2; kc++) {
#pragma unroll
            for (int c = 0; c < 2; c++) {
                int o = c * 4096 + tid * 16; // byte offset in 8KB chunk
                int r = o >> 6, cb = o & 63; // 64 B per row (32 bf16)
                int ldsb = c * 4096 + wave * 1024;
                gload16((const char*)A + ((size_t)(rowA + r) * K + k0 + kc * 32) * 2 + cb,
                        (char*)As0 + kc * 8192 + ldsb);
                gload16((const char*)Bt + ((size_t)(rowB + r) * K + k0 + kc * 32) * 2 + cb,
                        (char*)Bs0 + kc * 8192 + ldsb);
            }
        }
        __syncthreads();
#pragma unroll
        for (int kc = 0; kc < 2; kc++) {
            bf16x8 af[4], bfr[4];
#pragma unroll
            for (int i = 0; i < 4; i++) {
                af[i]  = *(const bf16x8*)(As0 + kc * 4096 + (wm + i * 16 + fr) * 32 + fo);
                bfr[i] = *(const bf16x8*)(Bs0 + kc * 4096 + (wn + i * 16 + fr) * 32 + fo);
            }
#pragma unroll
            for (int mi = 0; mi < 4; mi++)
#pragma unroll
                for (int ni = 0; ni < 4; ni++)
                    acc[mi][ni] = __builtin_amdgcn_mfma_f32_16x16x32_bf16(af[mi], bfr[ni],
                                                                          acc[mi][ni], 0, 0, 0);
        }
        __syncthreads();
    }

    const int cn = lane & 15, cm = (lane >> 4) * 4;
    for (int ni = 0; ni < 4; ni++) {
        int gn = rowB + wn + ni * 16 + cn;
        float bv = bias[gn];
        for (int mi = 0; mi < 4; mi++) {
#pragma unroll
            for (int r = 0; r < 4; r++) {
                int gm = rowA + wm + mi * 16 + cm + r;
                Cf[(size_t)gm * N + gn] = acc[mi][ni][r] + bv;
            }
        }
    }
}

// ---- softmax + PV for one q-tile: exp2 of S^T C-frag, pack to bf16 (= PV A-frag), 2 MFMAs/dt
__device__ inline void softmax_pv(const f32x16& cfrag, const bf16x8 vf[2][2],
                                  f32x16& o0, f32x16& o1, float& psum) {
    unsigned int pk[8];
    float es[8];
#pragma unroll
    for (int p = 0; p < 8; p++) {
        float e0 = __builtin_amdgcn_exp2f(cfrag[2 * p]);
        float e1 = __builtin_amdgcn_exp2f(cfrag[2 * p + 1]);
        es[p] = e0 + e1;
        pk[p] = packbf2(e0, e1);
    }
    psum += ((es[0] + es[1]) + (es[2] + es[3])) + ((es[4] + es[5]) + (es[6] + es[7]));
    u32x4 lo = {pk[0], pk[1], pk[2], pk[3]};
    u32x4 hi = {pk[4], pk[5], pk[6], pk[7]};
    bf16x8 pa0 = __builtin_bit_cast(bf16x8, lo); // keys [ku*32, +16) permuted
    bf16x8 pa1 = __builtin_bit_cast(bf16x8, hi); // keys [ku*32+16, +16)
    o0 = __builtin_amdgcn_mfma_f32_32x32x16_bf16(pa0, vf[0][0], o0, 0, 0, 0);
    o1 = __builtin_amdgcn_mfma_f32_32x32x16_bf16(pa0, vf[0][1], o1, 0, 0, 0);
    o0 = __builtin_amdgcn_mfma_f32_32x32x16_bf16(pa1, vf[1][0], o0, 0, 0, 0);
    o1 = __builtin_amdgcn_mfma_f32_32x32x16_bf16(pa1, vf[1][1], o1, 0, 0, 0);
}

// ---- one 32-key step, qt-interleaved (R8-proven)
__device__ inline void attn_step(const bf16x8 kf[4], const bf16x8 vf[2][2],
                                 const bf16x8 qf[2][4], f32x16 oacc[2][2], float psum[2]) {
    f32x16 cf0 = {}, cf1 = {};
#pragma unroll
    for (int ks = 0; ks < 4; ks++)
        cf0 = __builtin_amdgcn_mfma_f32_32x32x16_bf16(kf[ks], qf[0][ks], cf0, 0, 0, 0);
#pragma unroll
    for (int ks = 0; ks < 4; ks++)
        cf1 = __builtin_amdgcn_mfma_f32_32x32x16_bf16(kf[ks], qf[1][ks], cf1, 0, 0, 0);
    softmax_pv(cf0, vf, oacc[0][0], oacc[0][1], psum[0]);
    softmax_pv(cf1, vf, oacc[1][0], oacc[1][1], psum[1]);
}

// ---------------- flash attention v11 (R8-proven, settled local optimum) -------------------
// 64q x 64d per wave at 2 waves/SIMD (~190 regs). Four structural variations regressed:
//   R2 cap128 -> spill 1.5GB; R4 cap170 -> spill 60MB; R7 32q tile -> intensity halved;
//   R9 MFMA-ones denominator -> +25% MFMA work > VALU savings.
// Do NOT shrink the tile / add min-waves hints / move the denominator to MFMA.
__global__ __launch_bounds__(256, 2) void attn_kernel(const unsigned short* __restrict__ Qb, // [8192][1024] prescaled
                                                      const unsigned short* __restrict__ Kp,
                                                      const unsigned short* __restrict__ Vp,
                                                      unsigned short* __restrict__ attnb) { // [8192][1024]
    __shared__ float Po[2][8 * 256]; // [qpair] partial O (one qt round at a time)
    __shared__ float Pl[2][128];     // [qpair] partial psum[2] per lane
    const int tid = threadIdx.x;
    const int lane = tid & 63, wave = tid >> 6;
    const int qpair = wave >> 1, ksplit = wave & 1;
    const int m31 = lane & 31, h = lane >> 5;
    const int gflat = blockIdx.y * gridDim.x + blockIdx.x; // [0, 1024)
    const int xcd = gflat & 7, slot = gflat >> 3;          // slot in [0, 128)
    const int by = xcd * 8 + (slot >> 4);                  // [0, 64): 8 panels/XCD
    const int qb = slot & 15;                              // [0, 16)
    const int b = by >> 4;
    const int bS = b * SEQ, hcol = (by & 15) * HDIM;
    const int q0 = qb * 128 + qpair * 64;

    bf16x8 qf[2][4];
#pragma unroll
    for (int qt = 0; qt < 2; qt++)
#pragma unroll
        for (int ks = 0; ks < 4; ks++)
            qf[qt][ks] = *(const bf16x8*)(Qb + (size_t)(bS + q0 + qt * 32 + m31) * 1024 +
                                          hcol + ks * 16 + h * 8);

    f32x16 oacc[2][2] = {}; // [qt][dt]: C row=q, col=d=dt*32+m31
    float psum[2] = {0.f, 0.f};

    const unsigned short* kbase = Kp + (size_t)by * 64 * 2048 + lane * 8;
    const unsigned short* vbase = Vp + (size_t)by * 128 * 1024 + lane * 8;

    const int ku0 = ksplit * 32; // each wave: 32 key-units of 32 keys
    bf16x8 kfa[4], kfb[4];
    {
        const unsigned short* kp = kbase + (size_t)ku0 * 2048;
#pragma unroll
        for (int ks = 0; ks < 4; ks++) kfa[ks] = *(const bf16x8*)(kp + ks * 512);
    }
    for (int ki = 0; ki < 32; ki += 2) {
        // even step: compute with kfa, prefetch K(ki+1) -> kfb
        {
            int ku = ku0 + ki;
            bf16x8 vf[2][2];
#pragma unroll
            for (int ks = 0; ks < 2; ks++) {
                const unsigned short* vp = vbase + ((size_t)ku * 2 + ks) * 1024;
                vf[ks][0] = *(const bf16x8*)(vp);
                vf[ks][1] = *(const bf16x8*)(vp + 512);
            }
            const unsigned short* kpn = kbase + (size_t)(ku + 1) * 2048;
#pragma unroll
            for (int ks = 0; ks < 4; ks++) kfb[ks] = *(const bf16x8*)(kpn + ks * 512);
            attn_step(kfa, vf, qf, oacc, psum);
        }
        // odd step: compute with kfb, prefetch K(ki+2) -> kfa (clamped, branchless)
        {
            int ku = ku0 + ki + 1;
            bf16x8 vf[2][2];
#pragma unroll
            for (int ks = 0; ks < 2; ks++) {
                const unsigned short* vp = vbase + ((size_t)ku * 2 + ks) * 1024;
                vf[ks][0] = *(const bf16x8*)(vp);
                vf[ks][1] = *(const bf16x8*)(vp + 512);
            }
            int kup = ku0 + ((ki + 2 < 32) ? (ki + 2) : 31); // last iter: redundant reload
            const unsigned short* kpn = kbase + (size_t)kup * 2048;
#pragma unroll
            for (int ks = 0; ks < 4; ks++) kfa[ks] = *(const bf16x8*)(kpn + ks * 512);
            attn_step(kfb, vf, qf, oacc, psum);
        }
    }

    // two-round combine (qt=0 then qt=1): ksplit=1 parks partials, ksplit=0 sums.
#pragma unroll
    for (int qt = 0; qt < 2; qt++) {
        if (ksplit == 1) {
#pragma unroll
            for (int dt = 0; dt < 2; dt++)
#pragma unroll
                for (int c = 0; c < 4; c++) {
                    f32x4 v = {oacc[qt][dt][c * 4 + 0], oacc[qt][dt][c * 4 + 1],
                               oacc[qt][dt][c * 4 + 2], oacc[qt][dt][c * 4 + 3]};
                    *(f32x4*)&Po[qpair][(dt * 4 + c) * 256 + lane * 4] = v;
                }
            if (qt == 0)
                *(float2*)&Pl[qpair][lane * 2] = make_float2(psum[0], psum[1]);
        }
        __syncthreads();
        if (ksplit == 0) {
#pragma unroll
            for (int dt = 0; dt < 2; dt++)
#pragma unroll
                for (int c = 0; c < 4; c++) {
                    f32x4 v = *(const f32x4*)&Po[qpair][(dt * 4 + c) * 256 + lane * 4];
#pragma unroll
                    for (int j = 0; j < 4; j++) oacc[qt][dt][c * 4 + j] += v[j];
                }
            if (qt == 0) {
                float2 pl = *(const float2*)&Pl[qpair][lane * 2];
                psum[0] += pl.x; psum[1] += pl.y;
            }
        }
        if (qt == 0) __syncthreads(); // Po reused by round 2
    }

    if (ksplit == 0) {
        // epilogue: l[q] = psum(h=0)+psum(h=1); C rows: row=(r&3)+8*(r>>2)+4h
#pragma unroll
        for (int qt = 0; qt < 2; qt++) {
            float lt = psum[qt] + __shfl_xor(psum[qt], 32, 64);
            float rl = 1.f / lt; // valid on lanes where m31 == q
#pragma unroll
            for (int r = 0; r < 16; r++) {
                int row = (r & 3) + 8 * (r >> 2) + 4 * h;
                float rlr = __shfl(rl, row, 64);
                size_t orow = (size_t)(bS + q0 + qt * 32 + row) * 1024 + hcol;
                attnb[orow + m31]      = f2bf(oacc[qt][0][r] * rlr);
                attnb[orow + 32 + m31] = f2bf(oacc[qt][1][r] * rlr);
            }
        }
    }
}

extern "C" void kernel_launch(void* const* d_in, const int* in_sizes, int n_in,
                              void* d_out, int out_size, void* d_ws, size_t ws_size,
                              hipStream_t stream) {
    const float* x      = (const float*)d_in[0]; // [4,2048,1024]
    const float* W_qkv  = (const float*)d_in[1]; // [1024,3072]
    const float* b_qkv  = (const float*)d_in[2]; // [3072]
    const float* W_proj = (const float*)d_in[3]; // [1024,1024]
    const float* b_proj = (const float*)d_in[4]; // [1024]
    float* out = (float*)d_out;                  // [4,2048,1024]

    char* ws = (char*)d_ws;
    // lifetimes: x_bf,WqkvT die after gemm1 (Kp/Vp written DURING gemm1 -> own regions);
    // attnb aliases x_bf. Peak 75.5 MiB.
    unsigned short* x_bf   = (unsigned short*)(ws);                // [0, 16.8M)
    unsigned short* WqkvT  = (unsigned short*)(ws + 16777216);     // [16.8M, 23.1M)
    unsigned short* Qb     = (unsigned short*)(ws + 23068672);     // [23.1M, 39.8M)
    unsigned short* Kp     = (unsigned short*)(ws + 39845888);     // [39.8M, 56.6M)
    unsigned short* Vp     = (unsigned short*)(ws + 56623104);     // [56.6M, 73.4M)
    unsigned short* WprojT = (unsigned short*)(ws + 73400320);     // [73.4M, 75.5M)
    unsigned short* attnb  = (unsigned short*)(ws);                // reuses x_bf

    // 1) fused prologue: cast x + transpose W_qkv (Q cols pre-scaled) + transpose W_proj
    prologue<<<12288, 256, 0, stream>>>(x, x_bf, W_qkv, WqkvT, W_proj, WprojT);

    // 2) qkv = x @ W_qkv + b_qkv -> Qb (bf16, scaled) + Kp/Vp (fragment-packed), 8-phase 256^2
    qkv_gemm_pack<<<dim3(12, 32), 512, 0, stream>>>(x_bf, WqkvT, b_qkv, Qb, Kp, Vp);

    // 3) attention (x_bf dead; attnb reuses it): 128 q/block, KV split across wave pairs
    attn_kernel<<<dim3(SEQ / 128, BATCH * NHEADS), 256, 0, stream>>>(Qb, Kp, Vp, attnb);

    // 4) out = attn @ W_proj + b_proj (fp32 out), 128^2 kernel (256^2 would be 0.5 blocks/CU)
    gemm_bt_bias<<<dim3(DIM / 128, ROWS / 128), 256, 0, stream>>>(
        attnb, WprojT, b_proj, out, ROWS, DIM, DIM);
}

// Round 11
// 257.291 us; speedup vs baseline: 1.0563x; 1.0162x over previous
//
#include <hip/hip_runtime.h>
#include <hip/hip_bf16.h>

typedef __attribute__((ext_vector_type(8))) __bf16 bf16x8;
typedef __attribute__((ext_vector_type(4))) float f32x4;
typedef __attribute__((ext_vector_type(16))) float f32x16;
typedef __attribute__((ext_vector_type(4))) unsigned int u32x4;

#define DIM 1024
#define NHEADS 16
#define HDIM 64
#define BATCH 4
#define SEQ 2048
#define ROWS (BATCH * SEQ) /* 8192 */
#define SCL 0.18033688011112042f /* 0.125 * log2(e) */

__device__ inline unsigned short f2bf(float f) {
    __hip_bfloat16 h = __float2bfloat16(f);
    return *reinterpret_cast<unsigned short*>(&h);
}

// pack two floats to bf16x2 (RNE) -- v_cvt_pk_bf16_f32 on gfx950
__device__ inline unsigned int packbf2(float a, float b) {
    unsigned short ua = __builtin_bit_cast(unsigned short, (__bf16)a);
    unsigned short ub = __builtin_bit_cast(unsigned short, (__bf16)b);
    return (unsigned int)ua | ((unsigned int)ub << 16);
}

typedef const __attribute__((address_space(1))) unsigned int* gas_ptr;
typedef __attribute__((address_space(3))) unsigned int* las_ptr;
__device__ inline void gload16(const void* g, void* l) {
    __builtin_amdgcn_global_load_lds((gas_ptr)g, (las_ptr)l, 16, 0, 0);
}

// ---------------- fused prologue: cast x + transpose both weights (1 dispatch) -------------
__global__ __launch_bounds__(256) void prologue(const float* __restrict__ x,
                                                unsigned short* __restrict__ x_bf,
                                                const float* __restrict__ W_qkv,
                                                unsigned short* __restrict__ WqkvT,
                                                const float* __restrict__ W_proj,
                                                unsigned short* __restrict__ WprojT) {
    __shared__ float tile[32][33];
    const int blk = blockIdx.x;
    if (blk < 8192) {
        int i = blk * 256 + threadIdx.x;
        float4 v = ((const float4*)x)[i];
        ushort4 o;
        o.x = f2bf(v.x); o.y = f2bf(v.y); o.z = f2bf(v.z); o.w = f2bf(v.w);
        ((ushort4*)x_bf)[i] = o;
        return;
    }
    const float* in; unsigned short* outp; int C, srows, bx, byy; float scl;
    if (blk < 11264) {
        int t = blk - 8192;
        in = W_qkv; outp = WqkvT; C = 3 * DIM; srows = DIM; scl = SCL;
        bx = t % 96; byy = t / 96;
    } else {
        int t = blk - 11264;
        in = W_proj; outp = WprojT; C = DIM; srows = 0; scl = 1.f;
        bx = t & 31; byy = t >> 5;
    }
    const int R = DIM;
    int c0 = bx * 32, r0 = byy * 32;
    int tx = threadIdx.x & 31, ty = threadIdx.x >> 5; // 32 x 8
#pragma unroll
    for (int i = 0; i < 32; i += 8) {
        int r = r0 + ty + i, c = c0 + tx;
        tile[ty + i][tx] = in[(size_t)r * C + c];
    }
    __syncthreads();
#pragma unroll
    for (int i = 0; i < 32; i += 8) {
        int orow = c0 + ty + i, oc = r0 + tx;
        float v = tile[tx][ty + i];
        if (orow < srows) v *= scl;
        outp[(size_t)orow * R + oc] = f2bf(v);
    }
}

// =================== gemm1: 256x256-tile 8-phase pipelined QKV GEMM + K/V pack ==============
// T3+T4 schedule (m201-derived): BK=64, 8 waves (2Mx4N), per-wave 128x64. LDS 128 KiB =
// 2 tile-buffers x (A 32K + B 32K); operand tiles split in 2 interleaved halves (A-halfL =
// rows {0-63,128-191}; B-halfL = cols bit5==0). Per tile u, 4 phases {ds_read transient
// subtile; issue 1 half-tile stage; barrier; setprio; 16 MFMA; setprio; barrier}; stage
// targets P1:AH(u+1) P2:BH(u+1) P3:AL(u+2) P4:BL(u+2); boundary vmcnt(4) (2 newest
// half-tiles may stay in flight; never 0 mid-loop). XOR-swizzle granule^=(slot&7) via
// inverse-swizzled GLOBAL source + swizzled ds_read (gload_lds dest linear).
// R11 fix: NO persistent B fragments -- each phase re-reads its subtile into transient
// regs (32 ds_read_b128/tile, was 24). R10's bfa+bfb+afq+acc ~240 regs at the 256 cap
// likely spilled/serialized, flattening the pipeline gain. Now ~210 regs.
__global__ __launch_bounds__(512, 2) void qkv_gemm_pack(const unsigned short* __restrict__ A,   // x_bf [8192][1024]
                                                        const unsigned short* __restrict__ Bt,  // WqkvT [3072][1024]
                                                        const float* __restrict__ bias,
                                                        unsigned short* __restrict__ Cq,
                                                        unsigned short* __restrict__ Kp,
                                                        unsigned short* __restrict__ Vp) {
    __shared__ __align__(16) char SMEM[131072];
    const int tid = threadIdx.x;
    const int lane = tid & 63, wave = tid >> 6;
    const int wr = wave >> 2, wc = wave & 3;
    const int fr = lane & 15, lh = lane >> 4;
    // XCD-chunk swizzle, nwg = 384 (%8==0)
    const int gflat = blockIdx.y * gridDim.x + blockIdx.x;
    const int bidx = (gflat & 7) * 48 + (gflat >> 3);
    const int bx = bidx % 12, byy = bidx / 12;
    const int rowA = byy * 256, colB = bx * 256;

    // staging: slot s = wave*8 + lane/8; src granule = (lane&7)^(s&7)
    const int sA = wave * 8 + (lane >> 3);
    const int arow0 = sA;
    const int crow0 = (sA & 31) + (sA >> 5) * 64;
    const int glb = ((lane & 7) ^ (lane >> 3)) * 16;
    // ds_read: reader slot&7 = fr&7; k-granules lh and 4+lh, swizzled
    const int ga0 = ((lh) ^ (fr & 7)) * 16;
    const int ga1 = ((4 + lh) ^ (fr & 7)) * 16;
    const int aoff = (wr * 64 + fr) * 128;
    const int boff = (wc * 32 + fr) * 128;

    f32x4 acc[8][4] = {};

    auto stA = [&](int tb, int h, int tt) {
        char* d = SMEM + tb * 65536 + h * 16384 + wave * 1024;
        const char* g0 = (const char*)A +
            (((size_t)(rowA + arow0 + h * 64)) * 1024 + (size_t)tt * 64) * 2 + glb;
        gload16(g0, d);
        gload16(g0 + (size_t)128 * 2048, d + 8192);
    };
    auto stB = [&](int tb, int h, int tt) {
        char* d = SMEM + tb * 65536 + 32768 + h * 16384 + wave * 1024;
        const char* g0 = (const char*)Bt +
            (((size_t)(colB + crow0 + h * 32)) * 1024 + (size_t)tt * 64) * 2 + glb;
        gload16(g0, d);
        gload16(g0 + (size_t)128 * 2048, d + 8192);
    };

    // prologue: tile0 (all 4 halves) + tile1 (AL, BL); newest 2 half-tiles may stay in flight
    stA(0, 0, 0); stB(0, 0, 0); stA(0, 1, 0); stB(0, 1, 0);
    stA(1, 0, 1); stB(1, 0, 1);
    asm volatile("s_waitcnt vmcnt(4)" ::: "memory");
    __builtin_amdgcn_s_barrier();

    bf16x8 afq[4][2];
    for (int u = 0; u < 16; ++u) {
        const int cur = u & 1;
        const char* Al = SMEM + cur * 65536;
        const char* Bl = SMEM + cur * 65536 + 32768;
        // ---- phase 1: read A-halfL + B-halfL (transient); MFMA (miL,niL); stage AH(u+1)
        {
            bf16x8 bfp[2][2];
#pragma unroll
            for (int i = 0; i < 4; i++) {
                afq[i][0] = *(const bf16x8*)(Al + aoff + i * 2048 + ga0);
                afq[i][1] = *(const bf16x8*)(Al + aoff + i * 2048 + ga1);
            }
#pragma unroll
            for (int j = 0; j < 2; j++) {
                bfp[j][0] = *(const bf16x8*)(Bl + boff + j * 2048 + ga0);
                bfp[j][1] = *(const bf16x8*)(Bl + boff + j * 2048 + ga1);
            }
            if (u + 1 < 16) stA(cur ^ 1, 1, u + 1);
            __builtin_amdgcn_s_barrier();
            __builtin_amdgcn_s_setprio(1);
#pragma unroll
            for (int i = 0; i < 4; i++)
#pragma unroll
                for (int j = 0; j < 2; j++) {
                    acc[i][j] = __builtin_amdgcn_mfma_f32_16x16x32_bf16(afq[i][0], bfp[j][0], acc[i][j], 0, 0, 0);
                    acc[i][j] = __builtin_amdgcn_mfma_f32_16x16x32_bf16(afq[i][1], bfp[j][1], acc[i][j], 0, 0, 0);
                }
            __builtin_amdgcn_s_setprio(0);
            __builtin_amdgcn_s_barrier();
        }
        // ---- phase 2: read B-halfH (transient); MFMA (miL,niH); stage BH(u+1)
        {
            bf16x8 bfp[2][2];
#pragma unroll
            for (int j = 0; j < 2; j++) {
                bfp[j][0] = *(const bf16x8*)(Bl + 16384 + boff + j * 2048 + ga0);
                bfp[j][1] = *(const bf16x8*)(Bl + 16384 + boff + j * 2048 + ga1);
            }
            if (u + 1 < 16) stB(cur ^ 1, 1, u + 1);
            __builtin_amdgcn_s_barrier();
            __builtin_amdgcn_s_setprio(1);
#pragma unroll
            for (int i = 0; i < 4; i++)
#pragma unroll
                for (int j = 0; j < 2; j++) {
                    acc[i][2 + j] = __builtin_amdgcn_mfma_f32_16x16x32_bf16(afq[i][0], bfp[j][0], acc[i][2 + j], 0, 0, 0);
                    acc[i][2 + j] = __builtin_amdgcn_mfma_f32_16x16x32_bf16(afq[i][1], bfp[j][1], acc[i][2 + j], 0, 0, 0);
                }
            __builtin_amdgcn_s_setprio(0);
            __builtin_amdgcn_s_barrier();
        }
        // ---- phase 3: read A-halfH (overwrite afq) + B-halfL again; MFMA (miH,niL); stage AL(u+2)
        {
            bf16x8 bfp[2][2];
#pragma unroll
            for (int i = 0; i < 4; i++) {
                afq[i][0] = *(const bf16x8*)(Al + 16384 + aoff + i * 2048 + ga0);
                afq[i][1] = *(const bf16x8*)(Al + 16384 + aoff + i * 2048 + ga1);
            }
#pragma unroll
            for (int j = 0; j < 2; j++) {
                bfp[j][0] = *(const bf16x8*)(Bl + boff + j * 2048 + ga0);
                bfp[j][1] = *(const bf16x8*)(Bl + boff + j * 2048 + ga1);
            }
            if (u + 2 < 16) stA(cur, 0, u + 2);
            __builtin_amdgcn_s_barrier();
            __builtin_amdgcn_s_setprio(1);
#pragma unroll
            for (int i = 0; i < 4; i++)
#pragma unroll
                for (int j = 0; j < 2; j++) {
                    acc[4 + i][j] = __builtin_amdgcn_mfma_f32_16x16x32_bf16(afq[i][0], bfp[j][0], acc[4 + i][j], 0, 0, 0);
                    acc[4 + i][j] = __builtin_amdgcn_mfma_f32_16x16x32_bf16(afq[i][1], bfp[j][1], acc[4 + i][j], 0, 0, 0);
                }
            __builtin_amdgcn_s_setprio(0);
            __builtin_amdgcn_s_barrier();
        }
        // ---- phase 4: read B-halfH again; MFMA (miH,niH); stage BL(u+2); boundary vmcnt
        {
            bf16x8 bfp[2][2];
#pragma unroll
            for (int j = 0; j < 2; j++) {
                bfp[j][0] = *(const bf16x8*)(Bl + 16384 + boff + j * 2048 + ga0);
                bfp[j][1] = *(const bf16x8*)(Bl + 16384 + boff + j * 2048 + ga1);
            }
            if (u + 2 < 16) stB(cur, 0, u + 2);
            __builtin_amdgcn_s_barrier();
            __builtin_amdgcn_s_setprio(1);
#pragma unroll
            for (int i = 0; i < 4; i++)
#pragma unroll
                for (int j = 0; j < 2; j++) {
                    acc[4 + i][2 + j] = __builtin_amdgcn_mfma_f32_16x16x32_bf16(afq[i][0], bfp[j][0], acc[4 + i][2 + j], 0, 0, 0);
                    acc[4 + i][2 + j] = __builtin_amdgcn_mfma_f32_16x16x32_bf16(afq[i][1], bfp[j][1], acc[4 + i][2 + j], 0, 0, 0);
                }
            __builtin_amdgcn_s_setprio(0);
            if (u < 14) asm volatile("s_waitcnt vmcnt(4)" ::: "memory");
            else        asm volatile("s_waitcnt vmcnt(0)" ::: "memory");
            __builtin_amdgcn_s_barrier();
        }
    }

    // ---------------- epilogue: Q store / K,V pack (wave-private LDS overlay) ----------------
    const int cm = (lane >> 4) * 4, cn = lane & 15;
    const int gn0 = colB + wc * 64; // wave's 64-col region, uniform Q/K/V class
    if (gn0 < 1024) {
        for (int ni = 0; ni < 4; ni++) {
            int gn = gn0 + ni * 16 + cn;
            float bv = bias[gn] * SCL;
            for (int mi = 0; mi < 8; mi++) {
#pragma unroll
                for (int r = 0; r < 4; r++) {
                    int gm = rowA + wr * 128 + mi * 16 + cm + r;
                    Cq[(size_t)gm * 1024 + gn] = f2bf(acc[mi][ni][r] + bv);
                }
            }
        }
    } else {
        const int mm = lane & 31, hh = lane >> 5;
        unsigned short* Lw = (unsigned short*)SMEM + wave * (64 * 72);
        for (int kg = 0; kg < 2; kg++) {
            for (int ni = 0; ni < 4; ni++) {
                float bv = bias[gn0 + ni * 16 + cn];
                for (int mi = 0; mi < 4; mi++) {
#pragma unroll
                    for (int r = 0; r < 4; r++)
                        Lw[(mi * 16 + cm + r) * 72 + ni * 16 + cn] =
                            f2bf(acc[kg * 4 + mi][ni][r] + bv);
                }
            }
            __builtin_amdgcn_s_waitcnt(0); // own ds_writes visible to own ds_reads
            const int keybase = rowA + wr * 128 + kg * 64;
            const int b = keybase >> 11, s0g = keybase & 2047;
            if (gn0 < 2048) {
                const int h = (gn0 - 1024) >> 6;
                const size_t by = (size_t)(b * 16 + h);
                const int kub = s0g >> 5;
#pragma unroll
                for (int f = 0; f < 8; f++) {
                    int ktl = f >> 2, ks = f & 3;
                    uint4 d = *(const uint4*)&Lw[(ktl * 32 + mm) * 72 + ks * 16 + hh * 8];
                    *(uint4*)(Kp + ((by * 64 + kub + ktl) * 4 + ks) * 512 + lane * 8) = d;
                }
            } else {
                const int h = (gn0 - 2048) >> 6;
                const size_t by = (size_t)(b * 16 + h);
                const int vub = s0g >> 4;
#pragma unroll
                for (int f = 0; f < 8; f++) {
                    int ksl = f >> 1, dt = f & 1;
                    unsigned short tmp[8];
#pragma unroll
                    for (int j = 0; j < 8; j++)
                        tmp[j] = Lw[(ksl * 16 + (j & 3) + 8 * (j >> 2) + 4 * hh) * 72 + dt * 32 + mm];
                    *(uint4*)(Vp + ((by * 128 + vub + ksl) * 2 + dt) * 512 + lane * 8) =
                        *(uint4*)tmp;
                }
            }
            __builtin_amdgcn_s_waitcnt(0); // drain reads before kg1 overwrites Lw
        }
    }
}

// ---------------- GEMM (128^2, R5-verified): used for gemm2 (fp32 out + bias) ----------------
__global__ __launch_bounds__(256) void gemm_bt_bias(const unsigned short* __restrict__ A,
                                                    const unsigned short* __restrict__ Bt,
                                                    const float* __restrict__ bias,
                                                    float* __restrict__ Cf,
                                                    int M, int N, int K) {
    __shared__ unsigned short SMEM[16384];
    unsigned short* As0 = SMEM;            // As[kc] = SMEM + kc*4096
    unsigned short* Bs0 = SMEM + 8192;     // Bs[kc] = SMEM + 8192 + kc*4096
    const int tid = threadIdx.x;
    const int lane = tid & 63, wave = tid >> 6;
    const int wm = (wave >> 1) * 64, wn = (wave & 1) * 64;
    const int nwg = gridDim.x * gridDim.y;
    const int gflat = blockIdx.y * gridDim.x + blockIdx.x;
    const int bidx = (gflat & 7) * (nwg >> 3) + (gflat >> 3); // contiguous chunk per XCD
    const int bx = bidx % gridDim.x, byy = bidx / gridDim.x;
    const int rowA = byy * 128, rowB = bx * 128;
    const int fr = lane & 15, fo = (lane >> 4) * 8;

    f32x4 acc[4][4] = {};

    for (int k0 = 0; k0 < K; k0 += 64) {
#pragma unroll
        for (int kc = 0; kc < 2; kc++) {
#pragma unroll
            for (int c = 0; c < 2; c++) {
                int o = c * 4096 + tid * 16; // byte offset in 8KB chunk
                int r = o >> 6, cb = o & 63; // 64 B per row (32 bf16)
                int ldsb = c * 4096 + wave * 1024;
                gload16((const char*)A + ((size_t)(rowA + r) * K + k0 + kc * 32) * 2 + cb,
                        (char*)As0 + kc * 8192 + ldsb);
                gload16((const char*)Bt + ((size_t)(rowB + r) * K + k0 + kc * 32) * 2 + cb,
                        (char*)Bs0 + kc * 8192 + ldsb);
            }
        }
        __syncthreads();
#pragma unroll
        for (int kc = 0; kc < 2; kc++) {
            bf16x8 af[4], bfr[4];
#pragma unroll
            for (int i = 0; i < 4; i++) {
                af[i]  = *(const bf16x8*)(As0 + kc * 4096 + (wm + i * 16 + fr) * 32 + fo);
                bfr[i] = *(const bf16x8*)(Bs0 + kc * 4096 + (wn + i * 16 + fr) * 32 + fo);
            }
#pragma unroll
            for (int mi = 0; mi < 4; mi++)
#pragma unroll
                for (int ni = 0; ni < 4; ni++)
                    acc[mi][ni] = __builtin_amdgcn_mfma_f32_16x16x32_bf16(af[mi], bfr[ni],
                                                                          acc[mi][ni], 0, 0, 0);
        }
        __syncthreads();
    }

    const int cn = lane & 15, cm = (lane >> 4) * 4;
    for (int ni = 0; ni < 4; ni++) {
        int gn = rowB + wn + ni * 16 + cn;
        float bv = bias[gn];
        for (int mi = 0; mi < 4; mi++) {
#pragma unroll
            for (int r = 0; r < 4; r++) {
                int gm = rowA + wm + mi * 16 + cm + r;
                Cf[(size_t)gm * N + gn] = acc[mi][ni][r] + bv;
            }
        }
    }
}

// ---- softmax + PV for one q-tile: exp2 of S^T C-frag, pack to bf16 (= PV A-frag), 2 MFMAs/dt
__device__ inline void softmax_pv(const f32x16& cfrag, const bf16x8 vf[2][2],
                                  f32x16& o0, f32x16& o1, float& psum) {
    unsigned int pk[8];
    float es[8];
#pragma unroll
    for (int p = 0; p < 8; p++) {
        float e0 = __builtin_amdgcn_exp2f(cfrag[2 * p]);
        float e1 = __builtin_amdgcn_exp2f(cfrag[2 * p + 1]);
        es[p] = e0 + e1;
        pk[p] = packbf2(e0, e1);
    }
    psum += ((es[0] + es[1]) + (es[2] + es[3])) + ((es[4] + es[5]) + (es[6] + es[7]));
    u32x4 lo = {pk[0], pk[1], pk[2], pk[3]};
    u32x4 hi = {pk[4], pk[5], pk[6], pk[7]};
    bf16x8 pa0 = __builtin_bit_cast(bf16x8, lo); // keys [ku*32, +16) permuted
    bf16x8 pa1 = __builtin_bit_cast(bf16x8, hi); // keys [ku*32+16, +16)
    o0 = __builtin_amdgcn_mfma_f32_32x32x16_bf16(pa0, vf[0][0], o0, 0, 0, 0);
    o1 = __builtin_amdgcn_mfma_f32_32x32x16_bf16(pa0, vf[0][1], o1, 0, 0, 0);
    o0 = __builtin_amdgcn_mfma_f32_32x32x16_bf16(pa1, vf[1][0], o0, 0, 0, 0);
    o1 = __builtin_amdgcn_mfma_f32_32x32x16_bf16(pa1, vf[1][1], o1, 0, 0, 0);
}

// ---- one 32-key step, qt-interleaved (R8-proven)
__device__ inline void attn_step(const bf16x8 kf[4], const bf16x8 vf[2][2],
                                 const bf16x8 qf[2][4], f32x16 oacc[2][2], float psum[2]) {
    f32x16 cf0 = {}, cf1 = {};
#pragma unroll
    for (int ks = 0; ks < 4; ks++)
        cf0 = __builtin_amdgcn_mfma_f32_32x32x16_bf16(kf[ks], qf[0][ks], cf0, 0, 0, 0);
#pragma unroll
    for (int ks = 0; ks < 4; ks++)
        cf1 = __builtin_amdgcn_mfma_f32_32x32x16_bf16(kf[ks], qf[1][ks], cf1, 0, 0, 0);
    softmax_pv(cf0, vf, oacc[0][0], oacc[0][1], psum[0]);
    softmax_pv(cf1, vf, oacc[1][0], oacc[1][1], psum[1]);
}

// ---------------- flash attention v11 (R8-proven, settled local optimum) -------------------
// 64q x 64d per wave at 2 waves/SIMD (~190 regs). Four structural variations regressed:
//   R2 cap128 -> spill 1.5GB; R4 cap170 -> spill 60MB; R7 32q tile -> intensity halved;
//   R9 MFMA-ones denominator -> +25% MFMA work > VALU savings.
// Do NOT shrink the tile / add min-waves hints / move the denominator to MFMA.
__global__ __launch_bounds__(256, 2) void attn_kernel(const unsigned short* __restrict__ Qb, // [8192][1024] prescaled
                                                      const unsigned short* __restrict__ Kp,
                                                      const unsigned short* __restrict__ Vp,
                                                      unsigned short* __restrict__ attnb) { // [8192][1024]
    __shared__ float Po[2][8 * 256]; // [qpair] partial O (one qt round at a time)
    __shared__ float Pl[2][128];     // [qpair] partial psum[2] per lane
    const int tid = threadIdx.x;
    const int lane = tid & 63, wave = tid >> 6;
    const int qpair = wave >> 1, ksplit = wave & 1;
    const int m31 = lane & 31, h = lane >> 5;
    const int gflat = blockIdx.y * gridDim.x + blockIdx.x; // [0, 1024)
    const int xcd = gflat & 7, slot = gflat >> 3;          // slot in [0, 128)
    const int by = xcd * 8 + (slot >> 4);                  // [0, 64): 8 panels/XCD
    const int qb = slot & 15;                              // [0, 16)
    const int b = by >> 4;
    const int bS = b * SEQ, hcol = (by & 15) * HDIM;
    const int q0 = qb * 128 + qpair * 64;

    bf16x8 qf[2][4];
#pragma unroll
    for (int qt = 0; qt < 2; qt++)
#pragma unroll
        for (int ks = 0; ks < 4; ks++)
            qf[qt][ks] = *(const bf16x8*)(Qb + (size_t)(bS + q0 + qt * 32 + m31) * 1024 +
                                          hcol + ks * 16 + h * 8);

    f32x16 oacc[2][2] = {}; // [qt][dt]: C row=q, col=d=dt*32+m31
    float psum[2] = {0.f, 0.f};

    const unsigned short* kbase = Kp + (size_t)by * 64 * 2048 + lane * 8;
    const unsigned short* vbase = Vp + (size_t)by * 128 * 1024 + lane * 8;

    const int ku0 = ksplit * 32; // each wave: 32 key-units of 32 keys
    bf16x8 kfa[4], kfb[4];
    {
        const unsigned short* kp = kbase + (size_t)ku0 * 2048;
#pragma unroll
        for (int ks = 0; ks < 4; ks++) kfa[ks] = *(const bf16x8*)(kp + ks * 512);
    }
    for (int ki = 0; ki < 32; ki += 2) {
        // even step: compute with kfa, prefetch K(ki+1) -> kfb
        {
            int ku = ku0 + ki;
            bf16x8 vf[2][2];
#pragma unroll
            for (int ks = 0; ks < 2; ks++) {
                const unsigned short* vp = vbase + ((size_t)ku * 2 + ks) * 1024;
                vf[ks][0] = *(const bf16x8*)(vp);
                vf[ks][1] = *(const bf16x8*)(vp + 512);
            }
            const unsigned short* kpn = kbase + (size_t)(ku + 1) * 2048;
#pragma unroll
            for (int ks = 0; ks < 4; ks++) kfb[ks] = *(const bf16x8*)(kpn + ks * 512);
            attn_step(kfa, vf, qf, oacc, psum);
        }
        // odd step: compute with kfb, prefetch K(ki+2) -> kfa (clamped, branchless)
        {
            int ku = ku0 + ki + 1;
            bf16x8 vf[2][2];
#pragma unroll
            for (int ks = 0; ks < 2; ks++) {
                const unsigned short* vp = vbase + ((size_t)ku * 2 + ks) * 1024;
                vf[ks][0] = *(const bf16x8*)(vp);
                vf[ks][1] = *(const bf16x8*)(vp + 512);
            }
            int kup = ku0 + ((ki + 2 < 32) ? (ki + 2) : 31); // last iter: redundant reload
            const unsigned short* kpn = kbase + (size_t)kup * 2048;
#pragma unroll
            for (int ks = 0; ks < 4; ks++) kfa[ks] = *(const bf16x8*)(kpn + ks * 512);
            attn_step(kfb, vf, qf, oacc, psum);
        }
    }

    // two-round combine (qt=0 then qt=1): ksplit=1 parks partials, ksplit=0 sums.
#pragma unroll
    for (int qt = 0; qt < 2; qt++) {
        if (ksplit == 1) {
#pragma unroll
            for (int dt = 0; dt < 2; dt++)
#pragma unroll
                for (int c = 0; c < 4; c++) {
                    f32x4 v = {oacc[qt][dt][c * 4 + 0], oacc[qt][dt][c * 4 + 1],
                               oacc[qt][dt][c * 4 + 2], oacc[qt][dt][c * 4 + 3]};
                    *(f32x4*)&Po[qpair][(dt * 4 + c) * 256 + lane * 4] = v;
                }
            if (qt == 0)
                *(float2*)&Pl[qpair][lane * 2] = make_float2(psum[0], psum[1]);
        }
        __syncthreads();
        if (ksplit == 0) {
#pragma unroll
            for (int dt = 0; dt < 2; dt++)
#pragma unroll
                for (int c = 0; c < 4; c++) {
                    f32x4 v = *(const f32x4*)&Po[qpair][(dt * 4 + c) * 256 + lane * 4];
#pragma unroll
                    for (int j = 0; j < 4; j++) oacc[qt][dt][c * 4 + j] += v[j];
                }
            if (qt == 0) {
                float2 pl = *(const float2*)&Pl[qpair][lane * 2];
                psum[0] += pl.x; psum[1] += pl.y;
            }
        }
        if (qt == 0) __syncthreads(); // Po reused by round 2
    }

    if (ksplit == 0) {
        // epilogue: l[q] = psum(h=0)+psum(h=1); C rows: row=(r&3)+8*(r>>2)+4h
#pragma unroll
        for (int qt = 0; qt < 2; qt++) {
            float lt = psum[qt] + __shfl_xor(psum[qt], 32, 64);
            float rl = 1.f / lt; // valid on lanes where m31 == q
#pragma unroll
            for (int r = 0; r < 16; r++) {
                int row = (r & 3) + 8 * (r >> 2) + 4 * h;
                float rlr = __shfl(rl, row, 64);
                size_t orow = (size_t)(bS + q0 + qt * 32 + row) * 1024 + hcol;
                attnb[orow + m31]      = f2bf(oacc[qt][0][r] * rlr);
                attnb[orow + 32 + m31] = f2bf(oacc[qt][1][r] * rlr);
            }
        }
    }
}

extern "C" void kernel_launch(void* const* d_in, const int* in_sizes, int n_in,
                              void* d_out, int out_size, void* d_ws, size_t ws_size,
                              hipStream_t stream) {
    const float* x      = (const float*)d_in[0]; // [4,2048,1024]
    const float* W_qkv  = (const float*)d_in[1]; // [1024,3072]
    const float* b_qkv  = (const float*)d_in[2]; // [3072]
    const float* W_proj = (const float*)d_in[3]; // [1024,1024]
    const float* b_proj = (const float*)d_in[4]; // [1024]
    float* out = (float*)d_out;                  // [4,2048,1024]

    char* ws = (char*)d_ws;
    // lifetimes: x_bf,WqkvT die after gemm1 (Kp/Vp written DURING gemm1 -> own regions);
    // attnb aliases x_bf. Peak 75.5 MiB.
    unsigned short* x_bf   = (unsigned short*)(ws);                // [0, 16.8M)
    unsigned short* WqkvT  = (unsigned short*)(ws + 16777216);     // [16.8M, 23.1M)
    unsigned short* Qb     = (unsigned short*)(ws + 23068672);     // [23.1M, 39.8M)
    unsigned short* Kp     = (unsigned short*)(ws + 39845888);     // [39.8M, 56.6M)
    unsigned short* Vp     = (unsigned short*)(ws + 56623104);     // [56.6M, 73.4M)
    unsigned short* WprojT = (unsigned short*)(ws + 73400320);     // [73.4M, 75.5M)
    unsigned short* attnb  = (unsigned short*)(ws);                // reuses x_bf

    // 1) fused prologue: cast x + transpose W_qkv (Q cols pre-scaled) + transpose W_proj
    prologue<<<12288, 256, 0, stream>>>(x, x_bf, W_qkv, WqkvT, W_proj, WprojT);

    // 2) qkv = x @ W_qkv + b_qkv -> Qb (bf16, scaled) + Kp/Vp (fragment-packed), 8-phase 256^2
    qkv_gemm_pack<<<dim3(12, 32), 512, 0, stream>>>(x_bf, WqkvT, b_qkv, Qb, Kp, Vp);

    // 3) attention (x_bf dead; attnb reuses it): 128 q/block, KV split across wave pairs
    attn_kernel<<<dim3(SEQ / 128, BATCH * NHEADS), 256, 0, stream>>>(Qb, Kp, Vp, attnb);

    // 4) out = attn @ W_proj + b_proj (fp32 out), 128^2 kernel (256^2 would be 0.5 blocks/CU)
    gemm_bt_bias<<<dim3(DIM / 128, ROWS / 128), 256, 0, stream>>>(
        attnb, WprojT, b_proj, out, ROWS, DIM, DIM);
}